// Round 4
// baseline (273.997 us; speedup 1.0000x reference)
//
#include <hip/hip_runtime.h>
#include <math.h>

#define D        128
#define KCODES   2048
#define NPTS     32768
#define AS       136         // halves per LDS point-row (128 + 8 pad)
#define INV_T    (1.0f / 0.9f)
#define LO_SCALE 4096.0f
#define LO_INV   (1.0f / 4096.0f)
#define CHUNK    64          // points staged per chunk
#define NCHUNK   8           // chunks per block -> 512 points per block
#define PSLICES  64
#define CSLICES  16          // 16 x 128 codes per block
#define CT       2           // code-tiles (of 16) per wave -> 32 codes/wave

typedef _Float16 half8 __attribute__((ext_vector_type(8)));
typedef _Float16 half4 __attribute__((ext_vector_type(4)));
typedef float    f32x4 __attribute__((ext_vector_type(4)));

// ---------------------------------------------------------------------------
// Prep: e_sq[c], fp16 hi/lo split of embed (lo pre-scaled), zero classacc.
// ---------------------------------------------------------------------------
__global__ void prep_kernel(const float* __restrict__ embed,
                            float* __restrict__ e_sq,
                            _Float16* __restrict__ e_hi,
                            _Float16* __restrict__ e_lo,
                            float* __restrict__ classacc) {
    const int c = blockIdx.x;
    const int t = threadIdx.x;  // 0..63
    float v0 = embed[(size_t)c * D + t];
    float v1 = embed[(size_t)c * D + 64 + t];
    _Float16 h0 = (_Float16)v0;
    _Float16 h1 = (_Float16)v1;
    e_hi[(size_t)c * D + t]      = h0;
    e_hi[(size_t)c * D + 64 + t] = h1;
    e_lo[(size_t)c * D + t]      = (_Float16)((v0 - (float)h0) * LO_SCALE);
    e_lo[(size_t)c * D + 64 + t] = (_Float16)((v1 - (float)h1) * LO_SCALE);
    float s = v0 * v0 + v1 * v1;
    #pragma unroll
    for (int off = 32; off > 0; off >>= 1) s += __shfl_down(s, off, 64);
    if (t == 0) {
        e_sq[c] = s;
        classacc[c] = 0.0f;
    }
}

// stage one 64-point chunk: fp32 x -> hi/lo halves in LDS
__device__ __forceinline__ void stage_x(const float4* __restrict__ x4,
                                        _Float16* ahi, _Float16* alo,
                                        int pbase, int tid) {
    #pragma unroll
    for (int it = 0; it < 8; ++it) {
        int j = tid + it * 256;       // 2048 float4 = 64 rows x 32
        int row = j >> 5;
        int d4 = j & 31;
        float4 v = x4[(size_t)(pbase + row) * 32 + d4];
        half4 h, l4;
        h.x = (_Float16)v.x; h.y = (_Float16)v.y;
        h.z = (_Float16)v.z; h.w = (_Float16)v.w;
        l4.x = (_Float16)((v.x - (float)h.x) * LO_SCALE);
        l4.y = (_Float16)((v.y - (float)h.y) * LO_SCALE);
        l4.z = (_Float16)((v.z - (float)h.z) * LO_SCALE);
        l4.w = (_Float16)((v.w - (float)h.w) * LO_SCALE);
        *(half4*)&ahi[row * AS + d4 * 4] = h;
        *(half4*)&alo[row * AS + d4 * 4] = l4;
    }
}

// ---------------------------------------------------------------------------
// Sweep A (code-resident): each wave holds 32 codes' B-frags in registers.
// Streams 512 points via LDS; per point computes partial (max, argmax, l)
// over this block's 128 codes; block-combines into [CSLICES][NPTS] partials.
// ---------------------------------------------------------------------------
__global__ __launch_bounds__(256, 4)
void sweepA_kernel(const float* __restrict__ x,
                   const _Float16* __restrict__ e_hi_g,
                   const _Float16* __restrict__ e_lo_g,
                   const float* __restrict__ e_sq_g,
                   float* __restrict__ pm, float* __restrict__ pl,
                   int* __restrict__ pidx) {
    __shared__ _Float16 ahi[CHUNK * AS];   // 17.4 KB
    __shared__ _Float16 alo[CHUNK * AS];   // 17.4 KB
    __shared__ float cm[4][CHUNK];
    __shared__ float cl[4][CHUNK];
    __shared__ int   ci[4][CHUNK];

    const int tid  = threadIdx.x;
    const int w    = tid >> 6;
    const int lane = tid & 63;
    const int col  = lane & 15;
    const int quad = lane >> 4;
    const int cslice = blockIdx.y;
    const int pbase0 = blockIdx.x * (CHUNK * NCHUNK);
    const int c0w = cslice * (4 * CT * 16) + w * (CT * 16);

    // resident B fragments + e_sq for this wave's 32 codes
    half8 bhi[CT][4], blo[CT][4];
    float esq_r[CT];
    #pragma unroll
    for (int ct = 0; ct < CT; ++ct) {
        esq_r[ct] = e_sq_g[c0w + 16 * ct + col];
        #pragma unroll
        for (int kk = 0; kk < 4; ++kk) {
            size_t off = (size_t)(c0w + 16 * ct + col) * D + kk * 32 + quad * 8;
            bhi[ct][kk] = *(const half8*)(e_hi_g + off);
            blo[ct][kk] = *(const half8*)(e_lo_g + off);
        }
    }

    const float4* x4 = (const float4*)x;

    for (int chunk = 0; chunk < NCHUNK; ++chunk) {
        const int pbase = pbase0 + chunk * CHUNK;
        __syncthreads();
        stage_x(x4, ahi, alo, pbase, tid);
        __syncthreads();

        #pragma unroll
        for (int p = 0; p < 4; ++p) {
            f32x4 chh[CT], cx[CT];
            #pragma unroll
            for (int ct = 0; ct < CT; ++ct) { chh[ct] = (f32x4){0,0,0,0}; cx[ct] = (f32x4){0,0,0,0}; }
            #pragma unroll
            for (int kk = 0; kk < 4; ++kk) {
                const int aoff = (16 * p + col) * AS + kk * 32 + quad * 8;
                half8 Ahi = *(const half8*)&ahi[aoff];
                half8 Alo = *(const half8*)&alo[aoff];
                #pragma unroll
                for (int ct = 0; ct < CT; ++ct) {
                    chh[ct] = __builtin_amdgcn_mfma_f32_16x16x32_f16(Ahi, bhi[ct][kk], chh[ct], 0, 0, 0);
                    cx[ct]  = __builtin_amdgcn_mfma_f32_16x16x32_f16(Ahi, blo[ct][kk], cx[ct], 0, 0, 0);
                    cx[ct]  = __builtin_amdgcn_mfma_f32_16x16x32_f16(Alo, bhi[ct][kk], cx[ct], 0, 0, 0);
                }
            }
            // epilogue: per lane, 4 point-rows x its col across CT code-tiles
            float lp[4] = {0.f, 0.f, 0.f, 0.f};
            float bv[4] = {-INFINITY, -INFINITY, -INFINITY, -INFINITY};
            int   bi4[4] = {0, 0, 0, 0};
            #pragma unroll
            for (int ct = 0; ct < CT; ++ct) {
                int code = c0w + 16 * ct + col;
                #pragma unroll
                for (int r = 0; r < 4; ++r) {
                    float s = 2.0f * (chh[ct][r] + cx[ct][r] * LO_INV) - esq_r[ct];
                    lp[r] += __expf(s * INV_T);
                    if (s > bv[r]) { bv[r] = s; bi4[r] = code; }  // ct ascends -> first index
                }
            }
            // reduce across the 16 cols
            #pragma unroll
            for (int r = 0; r < 4; ++r) {
                float v = bv[r]; int idx = bi4[r]; float l = lp[r];
                #pragma unroll
                for (int off = 8; off >= 1; off >>= 1) {
                    float ov = __shfl_xor(v, off, 16);
                    int   oi = __shfl_xor(idx, off, 16);
                    float ol = __shfl_xor(l, off, 16);
                    l += ol;
                    if (ov > v || (ov == v && oi < idx)) { v = ov; idx = oi; }
                }
                if (col == 0) {
                    int row = p * 16 + quad * 4 + r;
                    cm[w][row] = v; cl[w][row] = l; ci[w][row] = idx;
                }
            }
        }
        __syncthreads();
        if (tid < CHUNK) {
            float bm = cm[0][tid]; int bidx = ci[0][tid]; float l = cl[0][tid];
            #pragma unroll
            for (int ww = 1; ww < 4; ++ww) {   // waves ascend in code -> strict > keeps first
                float v = cm[ww][tid]; int idx = ci[ww][tid];
                l += cl[ww][tid];
                if (v > bm) { bm = v; bidx = idx; }
            }
            size_t o = (size_t)cslice * NPTS + pbase + tid;
            pm[o] = bm; pl[o] = l; pidx[o] = bidx;
        }
    }
}

// ---------------------------------------------------------------------------
// Combine: per point, reduce 16 code-slice partials -> r=1/sum(l), argmax.
// ---------------------------------------------------------------------------
__global__ void combine_kernel(const float* __restrict__ pm, const float* __restrict__ pl,
                               const int* __restrict__ pidx,
                               float* __restrict__ r_buf, int* __restrict__ idx_buf,
                               float* __restrict__ ind_out) {
    const int p = blockIdx.x * 256 + threadIdx.x;
    float bm = -INFINITY; int bi = 0; float l = 0.0f;
    #pragma unroll
    for (int sl = 0; sl < CSLICES; ++sl) {   // slices ascend in code
        size_t o = (size_t)sl * NPTS + p;
        float v = pm[o];
        l += pl[o];
        if (v > bm) { bm = v; bi = pidx[o]; }
    }
    r_buf[p] = 1.0f / l;
    idx_buf[p] = bi;
    ind_out[p] = (float)bi;
}

// ---------------------------------------------------------------------------
// Sweep B (code-resident): class accumulation into per-lane registers,
// one global atomicAdd per code per wave at the end.
// ---------------------------------------------------------------------------
__global__ __launch_bounds__(256, 4)
void sweepB_kernel(const float* __restrict__ x,
                   const _Float16* __restrict__ e_hi_g,
                   const _Float16* __restrict__ e_lo_g,
                   const float* __restrict__ e_sq_g,
                   const float* __restrict__ r_buf,
                   float* __restrict__ classacc) {
    __shared__ _Float16 ahi[CHUNK * AS];
    __shared__ _Float16 alo[CHUNK * AS];
    __shared__ float r_s[CHUNK];

    const int tid  = threadIdx.x;
    const int w    = tid >> 6;
    const int lane = tid & 63;
    const int col  = lane & 15;
    const int quad = lane >> 4;
    const int cslice = blockIdx.y;
    const int pbase0 = blockIdx.x * (CHUNK * NCHUNK);
    const int c0w = cslice * (4 * CT * 16) + w * (CT * 16);

    half8 bhi[CT][4], blo[CT][4];
    float esq_r[CT];
    #pragma unroll
    for (int ct = 0; ct < CT; ++ct) {
        esq_r[ct] = e_sq_g[c0w + 16 * ct + col];
        #pragma unroll
        for (int kk = 0; kk < 4; ++kk) {
            size_t off = (size_t)(c0w + 16 * ct + col) * D + kk * 32 + quad * 8;
            bhi[ct][kk] = *(const half8*)(e_hi_g + off);
            blo[ct][kk] = *(const half8*)(e_lo_g + off);
        }
    }

    const float4* x4 = (const float4*)x;
    float csum[CT] = {0.f, 0.f};

    for (int chunk = 0; chunk < NCHUNK; ++chunk) {
        const int pbase = pbase0 + chunk * CHUNK;
        __syncthreads();
        stage_x(x4, ahi, alo, pbase, tid);
        if (tid < CHUNK) r_s[tid] = r_buf[pbase + tid];
        __syncthreads();

        #pragma unroll
        for (int p = 0; p < 4; ++p) {
            f32x4 chh[CT], cx[CT];
            #pragma unroll
            for (int ct = 0; ct < CT; ++ct) { chh[ct] = (f32x4){0,0,0,0}; cx[ct] = (f32x4){0,0,0,0}; }
            #pragma unroll
            for (int kk = 0; kk < 4; ++kk) {
                const int aoff = (16 * p + col) * AS + kk * 32 + quad * 8;
                half8 Ahi = *(const half8*)&ahi[aoff];
                half8 Alo = *(const half8*)&alo[aoff];
                #pragma unroll
                for (int ct = 0; ct < CT; ++ct) {
                    chh[ct] = __builtin_amdgcn_mfma_f32_16x16x32_f16(Ahi, bhi[ct][kk], chh[ct], 0, 0, 0);
                    cx[ct]  = __builtin_amdgcn_mfma_f32_16x16x32_f16(Ahi, blo[ct][kk], cx[ct], 0, 0, 0);
                    cx[ct]  = __builtin_amdgcn_mfma_f32_16x16x32_f16(Alo, bhi[ct][kk], cx[ct], 0, 0, 0);
                }
            }
            float rr[4];
            #pragma unroll
            for (int r = 0; r < 4; ++r) rr[r] = r_s[p * 16 + quad * 4 + r];
            #pragma unroll
            for (int ct = 0; ct < CT; ++ct) {
                #pragma unroll
                for (int r = 0; r < 4; ++r) {
                    float s = 2.0f * (chh[ct][r] + cx[ct][r] * LO_INV) - esq_r[ct];
                    csum[ct] += __expf(s * INV_T) * rr[r];
                }
            }
        }
    }

    #pragma unroll
    for (int ct = 0; ct < CT; ++ct) {
        float v = csum[ct];
        v += __shfl_xor(v, 16, 64);
        v += __shfl_xor(v, 32, 64);
        if (quad == 0) atomicAdd(&classacc[c0w + 16 * ct + col], v);
    }
}

// ---------------------------------------------------------------------------
// Gather quantize rows.
// ---------------------------------------------------------------------------
__global__ void gather_kernel(const float* __restrict__ embed,
                              const int* __restrict__ idx_buf,
                              float* __restrict__ q_out) {
    const int j = blockIdx.x * 256 + threadIdx.x;   // one float4 each
    const int row = j >> 5;
    const int d4 = j & 31;
    reinterpret_cast<float4*>(q_out)[(size_t)row * 32 + d4] =
        reinterpret_cast<const float4*>(embed)[(size_t)idx_buf[row] * 32 + d4];
}

// ---------------------------------------------------------------------------
__global__ void finalize_kernel(const float* __restrict__ classacc,
                                float* __restrict__ loss_out, int N, int K) {
    __shared__ float red[256];
    const int tid = threadIdx.x;
    float s = 0.0f;
    const float invN = 1.0f / (float)N;
    for (int i = tid; i < K; i += 256) {
        float cp = classacc[i] * invN;
        s += cp * logf(cp + 1e-6f);
    }
    red[tid] = s;
    __syncthreads();
    for (int off = 128; off > 0; off >>= 1) {
        if (tid < off) red[tid] += red[tid + off];
        __syncthreads();
    }
    if (tid == 0) loss_out[0] = red[0];
}

extern "C" void kernel_launch(void* const* d_in, const int* in_sizes, int n_in,
                              void* d_out, int out_size, void* d_ws, size_t ws_size,
                              hipStream_t stream) {
    const float* x     = (const float*)d_in[0];
    const float* embed = (const float*)d_in[1];

    float* out      = (float*)d_out;
    float* q_out    = out;
    float* ind_out  = out + (size_t)NPTS * D;
    float* loss_out = ind_out + NPTS;

    float*    e_sq  = (float*)d_ws;                       // K
    float*    cacc  = e_sq + KCODES;                      // K
    _Float16* e_hi  = (_Float16*)(cacc + KCODES);         // K*D
    _Float16* e_lo  = e_hi + (size_t)KCODES * D;          // K*D
    float*    pm    = (float*)(e_lo + (size_t)KCODES * D);// 16*N
    float*    pl    = pm + (size_t)CSLICES * NPTS;        // 16*N
    int*      pidx  = (int*)(pl + (size_t)CSLICES * NPTS);// 16*N
    float*    r_buf = (float*)(pidx + (size_t)CSLICES * NPTS); // N
    int*      idx_buf = (int*)(r_buf + NPTS);             // N

    dim3 sgrid(PSLICES, CSLICES);

    prep_kernel<<<KCODES, 64, 0, stream>>>(embed, e_sq, e_hi, e_lo, cacc);
    sweepA_kernel<<<sgrid, 256, 0, stream>>>(x, e_hi, e_lo, e_sq, pm, pl, pidx);
    combine_kernel<<<NPTS / 256, 256, 0, stream>>>(pm, pl, pidx, r_buf, idx_buf, ind_out);
    sweepB_kernel<<<sgrid, 256, 0, stream>>>(x, e_hi, e_lo, e_sq, r_buf, cacc);
    gather_kernel<<<NPTS * 32 / 256, 256, 0, stream>>>(embed, idx_buf, q_out);
    finalize_kernel<<<1, 256, 0, stream>>>(cacc, loss_out, NPTS, KCODES);
}